// Round 6
// baseline (227.838 us; speedup 1.0000x reference)
//
#include <hip/hip_runtime.h>
#include <stdint.h>

typedef unsigned int u32;
typedef unsigned short u16;
typedef __attribute__((ext_vector_type(8))) _Float16 f16x8;
typedef __attribute__((ext_vector_type(16))) float f32x16;
typedef __attribute__((ext_vector_type(4))) float f32x4;

#define DEVI __device__ __forceinline__

// ---------------- numeric helpers ----------------
DEVI u16 f2h(float f) {  // f32 -> f16 RNE (v_cvt_f16_f32)
  _Float16 h = (_Float16)f;
  return __builtin_bit_cast(u16, h);
}

// ---------------- ws layout (bytes) ----------------
#define WS_E16 0             // f16 E, [1024 rows][512]
#define WS_A (3u << 20)      // f32 a = E@Wa
#define WS_C (5u << 20)      // f32 c = E@Wb
#define WS_WF (7u << 20)     // f16 Wc/Wd fragment-major, 1MB (k_pair B regs)

// ---------------- kernel 0 (R16: merged prep) -------------------------------
// R15 left 65us outside k_pair: k_cvt -> k_ac -> k_pair serialization of two
// tiny kernels (~15-20us of real work). k_ac only depended on k_cvt for the
// f16 conversions (E16/WT); converting f32->f16 with the same RNE f2h during
// k_ac's own LDS staging yields bitwise-identical Aw/Cw and kills the
// dependency. WT had no other consumer since R14 (k_pair uses WF) -> deleted.
// One kernel, three independent block ranges:
//   [0,512):   E f32 -> E16, + out zeroing (blocks 0..255)
//   [512,640): W1 k>=1024 tile -> WF fragment-major (Wc/Wd for k_pair)
//   [640,896): AC gemm (a = E@Wa, c = E@Wb) reading E/W1 f32 directly
__global__ __launch_bounds__(256) void k_prep(
    const float* __restrict__ E, u16* __restrict__ E16,
    const float* __restrict__ W1, u16* __restrict__ WFo,
    float* __restrict__ outz, float* __restrict__ Aw, float* __restrict__ Cw) {
  __shared__ __align__(16) char psmem[16640];  // max(64*65*4, 8192)
  if (blockIdx.x < 512) {
    int i = (blockIdx.x * blockDim.x + threadIdx.x) * 4;
    float4 v = *(const float4*)(E + i);
    ushort4 o;
    o.x = f2h(v.x); o.y = f2h(v.y); o.z = f2h(v.z); o.w = f2h(v.w);
    *(ushort4*)(E16 + i) = o;
    // fold output zeroing (atomic-combine target): 256 blocks x 1024 floats
    if (blockIdx.x < 256) {
      float4 z; z.x = 0.f; z.y = 0.f; z.z = 0.f; z.w = 0.f;
      *(float4*)(outz + (blockIdx.x * blockDim.x + threadIdx.x) * 4) = z;
    }
    return;
  }

  if (blockIdx.x < 640) {
    // ---- WF emission path (Wc/Wd only: kBase in [1024,2048)) ----
    float (*tile)[65] = (float(*)[65])psmem;
    int bid2 = blockIdx.x - 512;           // 0..127
    int t = threadIdx.x;
    int kBase = 1024 + (bid2 & 15) * 64;   // 16 k-tiles (upper half of W1)
    int chBase = (bid2 >> 4) * 64;         // 8 ch-tiles
    int cqv = bid2 >> 4;
    int lr = t >> 4, lc = (t & 15) * 4;
    for (int rr = 0; rr < 4; rr++) {
      int kr = lr + rr * 16;
      float4 v = *(const float4*)(W1 + (kBase + kr) * 512 + chBase + lc);
      tile[kr][lc] = v.x; tile[kr][lc + 1] = v.y;
      tile[kr][lc + 2] = v.z; tile[kr][lc + 3] = v.w;
    }
    __syncthreads();
    // WF byte offset = ((cq*32 + lk)*4 + f)*1024 + lane*16, f = ks*2 + cb.
    // Fragment value = W1[k0 + kf + e][cq*64 + cb*32 + (lane&31)], e=0..7,
    // kf = (ks*2 + (lane>>5))*8 — same halves as the pre-R14 LDS bfr path.
    int fidx = (t >> 6) & 3;  // frag f
    int l = t & 63;           // lane
    int cbl = (fidx & 1) * 32 + (l & 31);
    int kf = ((fidx >> 1) * 2 + (l >> 5)) * 8;
#pragma unroll
    for (int s = 0; s < 2; s++) {
      int k0 = kBase + s * 32;
      int lk = (k0 < 1536) ? (((k0 - 1024) >> 5) * 2)
                           : (((k0 - 1536) >> 5) * 2 + 1);
      int klocal = s * 32 + kf;
      u32 wv[4];
#pragma unroll
      for (int u2 = 0; u2 < 4; u2++) {
        u16 lo = f2h(tile[klocal + 2 * u2][cbl]);
        u16 hi = f2h(tile[klocal + 2 * u2 + 1][cbl]);
        wv[u2] = (u32)lo | ((u32)hi << 16);
      }
      uint4 st; st.x = wv[0]; st.y = wv[1]; st.z = wv[2]; st.w = wv[3];
      *(uint4*)((char*)WFo + (((cqv * 32 + lk) * 4 + fidx) * 1024 + l * 16)) = st;
    }
    return;
  }

  // ---- AC gemm path: a = E@Wa, c = E@Wb, f32 sources converted in staging --
  // 64x64 tiles, grid 16x16 (ab = bx + 16*by), 8KB LDS. Same staged values
  // and MFMA order as the previous k_ac -> bitwise-identical Aw/Cw.
  {
    int ab = blockIdx.x - 640;
    char* sA = psmem;         // [64 rows][32 k] f16, swizzled
    char* sB = psmem + 4096;  // [64 ch][32 k]
    const int tid = threadIdx.x;
    const int lane = tid & 63, wid = tid >> 6;
    const int wr2 = wid >> 1, wc2 = wid & 1;
    const int n = lane & 31, q = lane >> 5;
    const int rowBase = (ab >> 4) * 64;
    const int chBase = (ab & 15) * 64;
    const int halfOff = (chBase >= 512) ? 512 : 0;
    const int chSrc0 = chBase - halfOff;
    f32x16 acc;
#pragma unroll
    for (int e = 0; e < 16; e++) acc[e] = 0.f;
    const int srow = tid >> 2, spg = tid & 3;
    const int slg = spg ^ ((srow >> 1) & 3);
    for (int kc = 0; kc < 16; kc++) {
      const int k0 = kc * 32;
      __syncthreads();
      {  // sA: 8 consecutive d of E row, f32 -> f16 (same values as E16)
        const float* src = E + (rowBase + srow) * 512 + k0 + spg * 8;
        float4 v0 = *(const float4*)(src);
        float4 v1 = *(const float4*)(src + 4);
        uint4 st;
        st.x = (u32)f2h(v0.x) | ((u32)f2h(v0.y) << 16);
        st.y = (u32)f2h(v0.z) | ((u32)f2h(v0.w) << 16);
        st.z = (u32)f2h(v1.x) | ((u32)f2h(v1.y) << 16);
        st.w = (u32)f2h(v1.z) | ((u32)f2h(v1.w) << 16);
        *(uint4*)(sA + srow * 64 + slg * 16) = st;
      }
      {  // sB: 8 consecutive k of W1 column (stride-512 gather), f32 -> f16
        const float* src = W1 + (halfOff + k0 + spg * 8) * 512 + chSrc0 + srow;
        u32 w[4];
#pragma unroll
        for (int u = 0; u < 4; u++) {
          float lo = src[(2 * u) * 512];
          float hi = src[(2 * u + 1) * 512];
          w[u] = (u32)f2h(lo) | ((u32)f2h(hi) << 16);
        }
        uint4 st; st.x = w[0]; st.y = w[1]; st.z = w[2]; st.w = w[3];
        *(uint4*)(sB + srow * 64 + slg * 16) = st;
      }
      __syncthreads();
      for (int ks = 0; ks < 2; ks++) {
        int kg = ks * 2 + q;
        int row = wr2 * 32 + n;
        int ch = wc2 * 32 + n;
        f16x8 af = *(const f16x8*)(sA + row * 64 + ((kg ^ ((row >> 1) & 3)) * 16));
        f16x8 bf = *(const f16x8*)(sB + ch * 64 + ((kg ^ ((ch >> 1) & 3)) * 16));
        acc = __builtin_amdgcn_mfma_f32_32x32x16_f16(af, bf, acc, 0, 0, 0);
      }
    }
#pragma unroll
    for (int r = 0; r < 16; r++) {
      int rowl = (r & 3) + 8 * (r >> 2) + 4 * q;  // C/D layout (m74/m101)
      int rowg = rowBase + wr2 * 32 + rowl;
      int chg = chBase + wc2 * 32 + n;
      float v = acc[r];
      if (chg < 512) Aw[rowg * 512 + chg] = v;
      else Cw[rowg * 512 + chg - 512] = v;
    }
  }
}

// ---------------- kernel 2: pair kernel (f16, operand-swapped MFMA) ---------
// R15: operand-swapped MFMA -> pair on lanes, ch on regs; per-lane ch
// reduction (202 -> 160us). R16 epilogue polish:
//  (a) loop reorder: (cb,g) outer, rb inner -> the conflict-prone 16-row SJ
//      reads (cj/aj) and wv load once per (cb,g) instead of 4x; 160 -> 88
//      ds_read_b128 per lane.
//  (b) pad 264 -> 268 f32: SJ row stride bank step 8j -> 12j mod 32, 4-way
//      conflict -> free 2-way (m136). Per-rb accumulation order unchanged ->
//      bitwise-identical output.
#define EI_OFF 0             // 8 rows x 520 f16 (1040B) = 8320
#define EJ_OFF 8320          // 16 rows x 1040B = 16640 -> 24960
// epilogue overlays (valid after the post-main __syncthreads):
#define SI_OFF 0             // 16 rows x 268 f32: [0..7]=Aw_i, [8..15]=Cw_i
#define SJ_OFF 17152         // 32 rows x 268 f32: [0..15]=Cw_j+b1, [16..31]=Aw_j+b1
#define W2S_OFF 51456        // 1024 -> 52480
#define RED_OFF 52480        // 128 pairs x 5 slots f32 -> 55040
#define RED2_OFF 55040       // -> 57600
#define SMEM2 57600

// acc[4][2]=128 AGPR + bu/bv 32 + ~80 arch VGPR <= 256: 2 waves/SIMD max.
__global__ __launch_bounds__(256, 2) void k_pair(
    const u16* __restrict__ E16, const u16* __restrict__ WF,
    const float* __restrict__ Aw, const float* __restrict__ Cw,
    const float* __restrict__ b1, const float* __restrict__ w2,
    const float* __restrict__ b2, float* __restrict__ out) {
  __shared__ __align__(16) char smem[SMEM2];
  const int tid = threadIdx.x;
  const int lane = tid & 63, wid = tid >> 6;  // wid = ch-quarter owner
  const int n = lane & 31, q = lane >> 5;
  const int bb = blockIdx.z;
  const int ch0 = blockIdx.y * 256;

  // invert triangular tile index: f = tj*(tj+1) + ti, ti in [0, 2*tj+2)
  int f = blockIdx.x;
  int tj = (int)((__builtin_sqrtf(4.0f * (float)f + 1.0f) - 1.0f) * 0.5f);
  while ((tj + 1) * (tj + 2) <= f) tj++;
  while (tj * (tj + 1) > f) tj--;
  const int ti = f - tj * (tj + 1);
  const int bi0 = ti * 8;
  const int bj0 = tj * 16;

  // fragment-major B pointer for this wave's exclusive 64-ch chunk
  const int cq = blockIdx.y * 4 + wid;  // ch-quarter 0..7
  const f16x8* wfp = (const f16x8*)WF + cq * 8192 + lane;
  const f16x8* wfu = wfp;        // tile lk=0
  const f16x8* wfv = wfp + 256;  // tile lk=1

  f16x8 bu[4], bv[4];  // frag f = ks*2 + cb
  auto loadB = [&](f16x8 (&b)[4], const f16x8* p) {
#pragma unroll
    for (int f2 = 0; f2 < 4; f2++) b[f2] = p[f2 * 64];  // imm offsets 0..3KB
  };

  loadB(bu, wfu);  // tile 0 in flight

  // stage e-tiles f16 (rows 0..7 = e_i, 8..23 = e_j), 520-elem stride
  for (int s = tid; s < 1536; s += 256) {
    int row = s >> 6, c16 = s & 63;
    int grow = (row < 8) ? (bi0 + row) : (bj0 + row - 8);
    const u16* src = E16 + (bb * 256 + grow) * 512 + c16 * 8;
    int off = (row < 8) ? (EI_OFF + (row * 520 + c16 * 8) * 2)
                        : (EJ_OFF + ((row - 8) * 520 + c16 * 8) * 2);
    *(uint4*)(smem + off) = *(const uint4*)src;
  }
  __syncthreads();  // e-tiles visible to all waves
  loadB(bv, wfv);   // tile 1 in flight

  // lane n owns pairs (i = 2rb + (n>>4), j = n&15); k-half by q
  const u16* eip = (const u16*)(smem + EI_OFF) + (n >> 4) * 520;
  const u16* ejp = (const u16*)(smem + EJ_OFF) + (n & 15) * 520;

  f32x16 acc[4][2];
#pragma unroll
  for (int a = 0; a < 4; a++)
#pragma unroll
    for (int c = 0; c < 2; c++)
#pragma unroll
      for (int e = 0; e < 16; e++) acc[a][c][e] = 0.f;

  for (int m = 0; m < 16; m++) {
    const int dBase = m * 32;
    // ---- u-phase: consume bu (tile lk=2m) ----
#pragma unroll
    for (int ks = 0; ks < 2; ks++) {
      const int d0 = dBase + ks * 16 + q * 8;
      f16x8 eb = *(const f16x8*)(ejp + d0);
#pragma unroll
      for (int rb = 0; rb < 4; rb++) {
        f16x8 ea = *(const f16x8*)(eip + rb * 1040 + d0);  // rows (n>>4)+2rb
        f16x8 u = ea * eb;  // v_pk_mul_f16
#pragma unroll
        for (int cb = 0; cb < 2; cb++)
          acc[rb][cb] = __builtin_amdgcn_mfma_f32_32x32x16_f16(
              bu[ks * 2 + cb], u, acc[rb][cb], 0, 0, 0);  // SWAPPED args
      }
    }
    if (m < 15) {
      wfu += 512;        // -> tile lk=2m+2
      loadB(bu, wfu);    // WAR on bu orders this after the MFMAs above
    }
    // ---- v-phase: consume bv (tile lk=2m+1) ----
#pragma unroll
    for (int ks = 0; ks < 2; ks++) {
      const int d0 = dBase + ks * 16 + q * 8;
      f16x8 eb = *(const f16x8*)(ejp + d0);
#pragma unroll
      for (int rb = 0; rb < 4; rb++) {
        f16x8 ea = *(const f16x8*)(eip + rb * 1040 + d0);
        f16x8 dd = ea - eb;
        f16x8 vv = __builtin_elementwise_max(dd, -dd);  // v_pk_max_f16
#pragma unroll
        for (int cb = 0; cb < 2; cb++)
          acc[rb][cb] = __builtin_amdgcn_mfma_f32_32x32x16_f16(
              bv[ks * 2 + cb], vv, acc[rb][cb], 0, 0, 0);  // SWAPPED args
      }
    }
    if (m < 15) {
      wfv += 512;        // -> tile lk=2m+3
      loadB(bv, wfv);
    }
  }

  // ---- epilogue: per-lane ch reduction (acc: pair on lanes, ch on regs) ---
  // ch (within y-half) = wid*64 + cb*32 + (r&3) + 8*(r>>2) + 4*q.
  __syncthreads();  // e-tiles dead; overlay epilogue arrays
  float* SIp = (float*)(smem + SI_OFF);
  float* SJp = (float*)(smem + SJ_OFF);
  float* W2Sp = (float*)(smem + W2S_OFF);
  float* RED = (float*)(smem + RED_OFF);
  float* RED2 = (float*)(smem + RED2_OFF);
  {
    float b1v = b1[ch0 + tid];
    for (int ii = 0; ii < 8; ii++) {
      int gri = (bb * 256 + bi0 + ii) * 512 + ch0 + tid;
      SIp[ii * 268 + tid] = Aw[gri];
      SIp[(8 + ii) * 268 + tid] = Cw[gri];
    }
    for (int jj = 0; jj < 16; jj++) {
      int grj = (bb * 256 + bj0 + jj) * 512 + ch0 + tid;
      SJp[jj * 268 + tid] = Cw[grj] + b1v;
      SJp[(16 + jj) * 268 + tid] = Aw[grj] + b1v;
    }
    W2Sp[tid] = w2[ch0 + tid];
  }
  __syncthreads();

  const int jrow = n & 15, ihalf = n >> 4;
  float vfa[4] = {0.f, 0.f, 0.f, 0.f}, vta[4] = {0.f, 0.f, 0.f, 0.f};
#pragma unroll
  for (int cb = 0; cb < 2; cb++) {
#pragma unroll
    for (int g = 0; g < 4; g++) {
      const int chl = wid * 64 + cb * 32 + 8 * g + 4 * q;
      f32x4 cj = *(const f32x4*)(SJp + jrow * 268 + chl);         // Cw[j]+b1
      f32x4 aj = *(const f32x4*)(SJp + (16 + jrow) * 268 + chl);  // Aw[j]+b1
      f32x4 wv = *(const f32x4*)(W2Sp + chl);
#pragma unroll
      for (int rb = 0; rb < 4; rb++) {
        const int irow = rb * 2 + ihalf;
        f32x4 ai = *(const f32x4*)(SIp + irow * 268 + chl);        // Aw[i]
        f32x4 ci = *(const f32x4*)(SIp + (8 + irow) * 268 + chl);  // Cw[i]
#pragma unroll
        for (int t = 0; t < 4; t++) {
          float base = acc[rb][cb][g * 4 + t];
          float hf = base + ai[t] + cj[t];   // h(i,j)
          if (hf > 0.f) vfa[rb] += hf * wv[t];
          float ht = base + ci[t] + aj[t];   // h(j,i)
          if (ht > 0.f) vta[rb] += ht * wv[t];
        }
      }
    }
  }
#pragma unroll
  for (int rb = 0; rb < 4; rb++) {
    // q-halves hold complementary ch sets of the same pair: one swap-add
    float vf = vfa[rb] + __shfl_xor(vfa[rb], 32);
    float vt = vta[rb] + __shfl_xor(vta[rb], 32);
    const int irow = rb * 2 + ihalf;
    int p = irow * 16 + jrow;
    if (q == 0) RED[p * 5 + wid] = vf;
    else        RED2[p * 5 + wid] = vt;
  }

  __syncthreads();
  {
    int p = tid & 127;
    int gi = bi0 + (p >> 4), gj = bj0 + (p & 15);
    float half_b2 = 0.5f * b2[0];  // each ch-half block contributes half of b2
    if (tid < 128) {
      float s = half_b2;
      for (int u = 0; u < 4; u++) s += RED[p * 5 + u];
      if (gi <= gj) atomicAdd(out + (bb * 256 + gi) * 256 + gj, s);
    } else {
      float s = half_b2;
      for (int u = 0; u < 4; u++) s += RED2[p * 5 + u];
      if (gi < gj) atomicAdd(out + (bb * 256 + gj) * 256 + gi, s);
    }
  }
}

// ---------------- launcher ----------------
extern "C" void kernel_launch(void* const* d_in, const int* in_sizes, int n_in,
                              void* d_out, int out_size, void* d_ws, size_t ws_size,
                              hipStream_t stream) {
  const float* E = (const float*)d_in[0];
  const float* W1 = (const float*)d_in[1];
  const float* b1 = (const float*)d_in[2];
  const float* W2 = (const float*)d_in[3];
  const float* b2 = (const float*)d_in[4];
  float* out = (float*)d_out;
  char* ws = (char*)d_ws;
  u16* E16 = (u16*)(ws + WS_E16);
  float* Aw = (float*)(ws + WS_A);
  float* Cw = (float*)(ws + WS_C);
  u16* WF = (u16*)(ws + WS_WF);

  // single prep kernel: E-cvt + out-zero (0..511) | WF emission (512..639) |
  // AC gemm f32-direct (640..895) — all block ranges independent
  hipLaunchKernelGGL(k_prep, dim3(896), dim3(256), 0, stream, E, E16, W1, WF,
                     out, Aw, Cw);
  // 272 = # of 8x16 pair-tiles intersecting the upper triangle (tj*(tj+1)+ti)
  hipLaunchKernelGGL(k_pair, dim3(272, 2, 4), dim3(256), 0, stream,
                     E16, WF, Aw, Cw, b1, W2, b2, out);
}

// Round 7
// 223.122 us; speedup vs baseline: 1.0211x; 1.0211x over previous
//
#include <hip/hip_runtime.h>
#include <stdint.h>

typedef unsigned int u32;
typedef unsigned short u16;
typedef __attribute__((ext_vector_type(8))) _Float16 f16x8;
typedef __attribute__((ext_vector_type(16))) float f32x16;
typedef __attribute__((ext_vector_type(4))) float f32x4;

#define DEVI __device__ __forceinline__

// ---------------- numeric helpers ----------------
DEVI u16 f2h(float f) {  // f32 -> f16 RNE (v_cvt_f16_f32)
  _Float16 h = (_Float16)f;
  return __builtin_bit_cast(u16, h);
}

// ---------------- ws layout (bytes) ----------------
#define WS_E16 0             // f16 E, [1024 rows][512]
#define WS_A (3u << 20)      // f32 a = E@Wa
#define WS_C (5u << 20)      // f32 c = E@Wb
#define WS_WF (7u << 20)     // f16 Wc/Wd fragment-major, 1MB (k_pair B regs)

// ---------------- kernel 0 (merged prep) ------------------------------------
// Three independent block ranges:
//   [0,512):   E f32 -> E16, + out zeroing (blocks 0..255)
//   [512,640): W1 k>=1024 tile -> WF fragment-major (Wc/Wd for k_pair)
//   [640,896): AC gemm (a = E@Wa, c = E@Wb) reading E/W1 f32 directly
__global__ __launch_bounds__(256) void k_prep(
    const float* __restrict__ E, u16* __restrict__ E16,
    const float* __restrict__ W1, u16* __restrict__ WFo,
    float* __restrict__ outz, float* __restrict__ Aw, float* __restrict__ Cw) {
  __shared__ __align__(16) char psmem[16640];  // max(64*65*4, 8192)
  if (blockIdx.x < 512) {
    int i = (blockIdx.x * blockDim.x + threadIdx.x) * 4;
    float4 v = *(const float4*)(E + i);
    ushort4 o;
    o.x = f2h(v.x); o.y = f2h(v.y); o.z = f2h(v.z); o.w = f2h(v.w);
    *(ushort4*)(E16 + i) = o;
    // fold output zeroing (atomic-combine target): 256 blocks x 1024 floats
    if (blockIdx.x < 256) {
      float4 z; z.x = 0.f; z.y = 0.f; z.z = 0.f; z.w = 0.f;
      *(float4*)(outz + (blockIdx.x * blockDim.x + threadIdx.x) * 4) = z;
    }
    return;
  }

  if (blockIdx.x < 640) {
    // ---- WF emission path (Wc/Wd only: kBase in [1024,2048)) ----
    float (*tile)[65] = (float(*)[65])psmem;
    int bid2 = blockIdx.x - 512;           // 0..127
    int t = threadIdx.x;
    int kBase = 1024 + (bid2 & 15) * 64;   // 16 k-tiles (upper half of W1)
    int chBase = (bid2 >> 4) * 64;         // 8 ch-tiles
    int cqv = bid2 >> 4;
    int lr = t >> 4, lc = (t & 15) * 4;
    for (int rr = 0; rr < 4; rr++) {
      int kr = lr + rr * 16;
      float4 v = *(const float4*)(W1 + (kBase + kr) * 512 + chBase + lc);
      tile[kr][lc] = v.x; tile[kr][lc + 1] = v.y;
      tile[kr][lc + 2] = v.z; tile[kr][lc + 3] = v.w;
    }
    __syncthreads();
    // WF byte offset = ((cq*32 + lk)*4 + f)*1024 + lane*16, f = ks*2 + cb.
    // Fragment value = W1[k0 + kf + e][cq*64 + cb*32 + (lane&31)], e=0..7,
    // kf = (ks*2 + (lane>>5))*8 — same halves as the pre-R14 LDS bfr path.
    int fidx = (t >> 6) & 3;  // frag f
    int l = t & 63;           // lane
    int cbl = (fidx & 1) * 32 + (l & 31);
    int kf = ((fidx >> 1) * 2 + (l >> 5)) * 8;
#pragma unroll
    for (int s = 0; s < 2; s++) {
      int k0 = kBase + s * 32;
      int lk = (k0 < 1536) ? (((k0 - 1024) >> 5) * 2)
                           : (((k0 - 1536) >> 5) * 2 + 1);
      int klocal = s * 32 + kf;
      u32 wv[4];
#pragma unroll
      for (int u2 = 0; u2 < 4; u2++) {
        u16 lo = f2h(tile[klocal + 2 * u2][cbl]);
        u16 hi = f2h(tile[klocal + 2 * u2 + 1][cbl]);
        wv[u2] = (u32)lo | ((u32)hi << 16);
      }
      uint4 st; st.x = wv[0]; st.y = wv[1]; st.z = wv[2]; st.w = wv[3];
      *(uint4*)((char*)WFo + (((cqv * 32 + lk) * 4 + fidx) * 1024 + l * 16)) = st;
    }
    return;
  }

  // ---- AC gemm path: a = E@Wa, c = E@Wb, f32 sources converted in staging --
  // 64x64 tiles, grid 16x16 (ab = bx + 16*by), 8KB LDS. Same staged values
  // and MFMA order as the original k_ac -> bitwise-identical Aw/Cw.
  {
    int ab = blockIdx.x - 640;
    char* sA = psmem;         // [64 rows][32 k] f16, swizzled
    char* sB = psmem + 4096;  // [64 ch][32 k]
    const int tid = threadIdx.x;
    const int lane = tid & 63, wid = tid >> 6;
    const int wr2 = wid >> 1, wc2 = wid & 1;
    const int n = lane & 31, q = lane >> 5;
    const int rowBase = (ab >> 4) * 64;
    const int chBase = (ab & 15) * 64;
    const int halfOff = (chBase >= 512) ? 512 : 0;
    const int chSrc0 = chBase - halfOff;
    f32x16 acc;
#pragma unroll
    for (int e = 0; e < 16; e++) acc[e] = 0.f;
    const int srow = tid >> 2, spg = tid & 3;
    const int slg = spg ^ ((srow >> 1) & 3);
    for (int kc = 0; kc < 16; kc++) {
      const int k0 = kc * 32;
      __syncthreads();
      {  // sA: 8 consecutive d of E row, f32 -> f16 (same values as E16)
        const float* src = E + (rowBase + srow) * 512 + k0 + spg * 8;
        float4 v0 = *(const float4*)(src);
        float4 v1 = *(const float4*)(src + 4);
        uint4 st;
        st.x = (u32)f2h(v0.x) | ((u32)f2h(v0.y) << 16);
        st.y = (u32)f2h(v0.z) | ((u32)f2h(v0.w) << 16);
        st.z = (u32)f2h(v1.x) | ((u32)f2h(v1.y) << 16);
        st.w = (u32)f2h(v1.z) | ((u32)f2h(v1.w) << 16);
        *(uint4*)(sA + srow * 64 + slg * 16) = st;
      }
      {  // sB: 8 consecutive k of W1 column (stride-512 gather), f32 -> f16
        const float* src = W1 + (halfOff + k0 + spg * 8) * 512 + chSrc0 + srow;
        u32 w[4];
#pragma unroll
        for (int u = 0; u < 4; u++) {
          float lo = src[(2 * u) * 512];
          float hi = src[(2 * u + 1) * 512];
          w[u] = (u32)f2h(lo) | ((u32)f2h(hi) << 16);
        }
        uint4 st; st.x = w[0]; st.y = w[1]; st.z = w[2]; st.w = w[3];
        *(uint4*)(sB + srow * 64 + slg * 16) = st;
      }
      __syncthreads();
      for (int ks = 0; ks < 2; ks++) {
        int kg = ks * 2 + q;
        int row = wr2 * 32 + n;
        int ch = wc2 * 32 + n;
        f16x8 af = *(const f16x8*)(sA + row * 64 + ((kg ^ ((row >> 1) & 3)) * 16));
        f16x8 bf = *(const f16x8*)(sB + ch * 64 + ((kg ^ ((ch >> 1) & 3)) * 16));
        acc = __builtin_amdgcn_mfma_f32_32x32x16_f16(af, bf, acc, 0, 0, 0);
      }
    }
#pragma unroll
    for (int r = 0; r < 16; r++) {
      int rowl = (r & 3) + 8 * (r >> 2) + 4 * q;  // C/D layout (m74/m101)
      int rowg = rowBase + wr2 * 32 + rowl;
      int chg = chBase + wc2 * 32 + n;
      float v = acc[r];
      if (chg < 512) Aw[rowg * 512 + chg] = v;
      else Cw[rowg * 512 + chg - 512] = v;
    }
  }
}

// ---------------- kernel 2: pair kernel (f16, single-read u+v formation) ----
// R17: the u/v phases were RE-READING identical ea/eb addresses (same
// d0 = dBase+ks*16+q*8) — a redundancy introduced by R12's phase split (R0
// held afv in regs). Counters: main loop ~130us at ~45% matrix-pipe util,
// with the ds_read->form->MFMA chain exposing ~120-150cyc LDS latency at
// each of 4 ks-group heads per m. Fix: ONE read pass per (m,ks): read eb +
// ea[rb] once, form u AND vv together; u-MFMA burst immediately; vv held in
// a static-indexed f16x8 vvk[4] (+16 VGPR, est. peak ~225 < 256) and
// consumed in a v-MFMA burst right after. Per-m ds_reads 20 -> 10; MFMA
// burst per read-group 8 -> 16 (512cyc covers the next group's LDS latency).
// loadB(bu) issues between ks=1's u- and v-bursts so L2 latency is covered.
// Note: accumulation order within m becomes u(ks0),v(ks0),u(ks1),v(ks1)
// (was u,u,v,v) — rounding-level change only.
#define EI_OFF 0             // 8 rows x 520 f16 (1040B) = 8320
#define EJ_OFF 8320          // 16 rows x 1040B = 16640 -> 24960
// epilogue overlays (valid after the post-main __syncthreads):
#define SI_OFF 0             // 16 rows x 268 f32: [0..7]=Aw_i, [8..15]=Cw_i
#define SJ_OFF 17152         // 32 rows x 268 f32: [0..15]=Cw_j+b1, [16..31]=Aw_j+b1
#define W2S_OFF 51456        // 1024 -> 52480
#define RED_OFF 52480        // 128 pairs x 5 slots f32 -> 55040
#define RED2_OFF 55040       // -> 57600
#define SMEM2 57600

// acc[4][2]=128 AGPR + bu/bv 32 + vvk 16 + ~80 arch VGPR <= 256: 2 waves/SIMD.
__global__ __launch_bounds__(256, 2) void k_pair(
    const u16* __restrict__ E16, const u16* __restrict__ WF,
    const float* __restrict__ Aw, const float* __restrict__ Cw,
    const float* __restrict__ b1, const float* __restrict__ w2,
    const float* __restrict__ b2, float* __restrict__ out) {
  __shared__ __align__(16) char smem[SMEM2];
  const int tid = threadIdx.x;
  const int lane = tid & 63, wid = tid >> 6;  // wid = ch-quarter owner
  const int n = lane & 31, q = lane >> 5;
  const int bb = blockIdx.z;
  const int ch0 = blockIdx.y * 256;

  // invert triangular tile index: f = tj*(tj+1) + ti, ti in [0, 2*tj+2)
  int f = blockIdx.x;
  int tj = (int)((__builtin_sqrtf(4.0f * (float)f + 1.0f) - 1.0f) * 0.5f);
  while ((tj + 1) * (tj + 2) <= f) tj++;
  while (tj * (tj + 1) > f) tj--;
  const int ti = f - tj * (tj + 1);
  const int bi0 = ti * 8;
  const int bj0 = tj * 16;

  // fragment-major B pointer for this wave's exclusive 64-ch chunk
  const int cq = blockIdx.y * 4 + wid;  // ch-quarter 0..7
  const f16x8* wfp = (const f16x8*)WF + cq * 8192 + lane;
  const f16x8* wfu = wfp;        // tile lk=0
  const f16x8* wfv = wfp + 256;  // tile lk=1

  f16x8 bu[4], bv[4];  // frag f = ks*2 + cb
  auto loadB = [&](f16x8 (&b)[4], const f16x8* p) {
#pragma unroll
    for (int f2 = 0; f2 < 4; f2++) b[f2] = p[f2 * 64];  // imm offsets 0..3KB
  };

  loadB(bu, wfu);  // tile 0 in flight

  // stage e-tiles f16 (rows 0..7 = e_i, 8..23 = e_j), 520-elem stride
  for (int s = tid; s < 1536; s += 256) {
    int row = s >> 6, c16 = s & 63;
    int grow = (row < 8) ? (bi0 + row) : (bj0 + row - 8);
    const u16* src = E16 + (bb * 256 + grow) * 512 + c16 * 8;
    int off = (row < 8) ? (EI_OFF + (row * 520 + c16 * 8) * 2)
                        : (EJ_OFF + ((row - 8) * 520 + c16 * 8) * 2);
    *(uint4*)(smem + off) = *(const uint4*)src;
  }
  __syncthreads();  // e-tiles visible to all waves
  loadB(bv, wfv);   // tile 1 in flight

  // lane n owns pairs (i = 2rb + (n>>4), j = n&15); k-half by q
  const u16* eip = (const u16*)(smem + EI_OFF) + (n >> 4) * 520;
  const u16* ejp = (const u16*)(smem + EJ_OFF) + (n & 15) * 520;

  f32x16 acc[4][2];
#pragma unroll
  for (int a = 0; a < 4; a++)
#pragma unroll
    for (int c = 0; c < 2; c++)
#pragma unroll
      for (int e = 0; e < 16; e++) acc[a][c][e] = 0.f;

  for (int m = 0; m < 16; m++) {
    const int dBase = m * 32;
#pragma unroll
    for (int ks = 0; ks < 2; ks++) {
      const int d0 = dBase + ks * 16 + q * 8;
      f16x8 eb = *(const f16x8*)(ejp + d0);
      f16x8 vvk[4];  // |ea-eb| held for the v-burst (static-indexed)
      // ---- read + form + u-burst (tile lk=2m, bu) ----
#pragma unroll
      for (int rb = 0; rb < 4; rb++) {
        f16x8 ea = *(const f16x8*)(eip + rb * 1040 + d0);  // rows (n>>4)+2rb
        f16x8 u = ea * eb;  // v_pk_mul_f16
        f16x8 dd = ea - eb;
        vvk[rb] = __builtin_elementwise_max(dd, -dd);  // v_pk_max_f16
        acc[rb][0] = __builtin_amdgcn_mfma_f32_32x32x16_f16(
            bu[ks * 2 + 0], u, acc[rb][0], 0, 0, 0);
        acc[rb][1] = __builtin_amdgcn_mfma_f32_32x32x16_f16(
            bu[ks * 2 + 1], u, acc[rb][1], 0, 0, 0);
      }
      // bu fully consumed after ks=1's u-burst: prefetch under the v-burst
      if (ks == 1 && m < 15) {
        wfu += 512;      // -> tile lk=2m+2
        loadB(bu, wfu);  // WAR-ordered after the u-MFMAs above
      }
      // ---- v-burst (tile lk=2m+1, bv) from held vvk ----
#pragma unroll
      for (int rb = 0; rb < 4; rb++) {
        acc[rb][0] = __builtin_amdgcn_mfma_f32_32x32x16_f16(
            bv[ks * 2 + 0], vvk[rb], acc[rb][0], 0, 0, 0);
        acc[rb][1] = __builtin_amdgcn_mfma_f32_32x32x16_f16(
            bv[ks * 2 + 1], vvk[rb], acc[rb][1], 0, 0, 0);
      }
    }
    if (m < 15) {
      wfv += 512;      // -> tile lk=2m+3
      loadB(bv, wfv);  // consumed next m (ks0 v-burst): latency covered
    }
  }

  // ---- epilogue: per-lane ch reduction (acc: pair on lanes, ch on regs) ---
  // ch (within y-half) = wid*64 + cb*32 + (r&3) + 8*(r>>2) + 4*q.
  __syncthreads();  // e-tiles dead; overlay epilogue arrays
  float* SIp = (float*)(smem + SI_OFF);
  float* SJp = (float*)(smem + SJ_OFF);
  float* W2Sp = (float*)(smem + W2S_OFF);
  float* RED = (float*)(smem + RED_OFF);
  float* RED2 = (float*)(smem + RED2_OFF);
  {
    float b1v = b1[ch0 + tid];
    for (int ii = 0; ii < 8; ii++) {
      int gri = (bb * 256 + bi0 + ii) * 512 + ch0 + tid;
      SIp[ii * 268 + tid] = Aw[gri];
      SIp[(8 + ii) * 268 + tid] = Cw[gri];
    }
    for (int jj = 0; jj < 16; jj++) {
      int grj = (bb * 256 + bj0 + jj) * 512 + ch0 + tid;
      SJp[jj * 268 + tid] = Cw[grj] + b1v;
      SJp[(16 + jj) * 268 + tid] = Aw[grj] + b1v;
    }
    W2Sp[tid] = w2[ch0 + tid];
  }
  __syncthreads();

  const int jrow = n & 15, ihalf = n >> 4;
  float vfa[4] = {0.f, 0.f, 0.f, 0.f}, vta[4] = {0.f, 0.f, 0.f, 0.f};
#pragma unroll
  for (int cb = 0; cb < 2; cb++) {
#pragma unroll
    for (int g = 0; g < 4; g++) {
      const int chl = wid * 64 + cb * 32 + 8 * g + 4 * q;
      f32x4 cj = *(const f32x4*)(SJp + jrow * 268 + chl);         // Cw[j]+b1
      f32x4 aj = *(const f32x4*)(SJp + (16 + jrow) * 268 + chl);  // Aw[j]+b1
      f32x4 wv = *(const f32x4*)(W2Sp + chl);
#pragma unroll
      for (int rb = 0; rb < 4; rb++) {
        const int irow = rb * 2 + ihalf;
        f32x4 ai = *(const f32x4*)(SIp + irow * 268 + chl);        // Aw[i]
        f32x4 ci = *(const f32x4*)(SIp + (8 + irow) * 268 + chl);  // Cw[i]
#pragma unroll
        for (int t = 0; t < 4; t++) {
          float base = acc[rb][cb][g * 4 + t];
          float hf = base + ai[t] + cj[t];   // h(i,j)
          if (hf > 0.f) vfa[rb] += hf * wv[t];
          float ht = base + ci[t] + aj[t];   // h(j,i)
          if (ht > 0.f) vta[rb] += ht * wv[t];
        }
      }
    }
  }
#pragma unroll
  for (int rb = 0; rb < 4; rb++) {
    // q-halves hold complementary ch sets of the same pair: one swap-add
    float vf = vfa[rb] + __shfl_xor(vfa[rb], 32);
    float vt = vta[rb] + __shfl_xor(vta[rb], 32);
    const int irow = rb * 2 + ihalf;
    int p = irow * 16 + jrow;
    if (q == 0) RED[p * 5 + wid] = vf;
    else        RED2[p * 5 + wid] = vt;
  }

  __syncthreads();
  {
    int p = tid & 127;
    int gi = bi0 + (p >> 4), gj = bj0 + (p & 15);
    float half_b2 = 0.5f * b2[0];  // each ch-half block contributes half of b2
    if (tid < 128) {
      float s = half_b2;
      for (int u = 0; u < 4; u++) s += RED[p * 5 + u];
      if (gi <= gj) atomicAdd(out + (bb * 256 + gi) * 256 + gj, s);
    } else {
      float s = half_b2;
      for (int u = 0; u < 4; u++) s += RED2[p * 5 + u];
      if (gi < gj) atomicAdd(out + (bb * 256 + gj) * 256 + gi, s);
    }
  }
}

// ---------------- launcher ----------------
extern "C" void kernel_launch(void* const* d_in, const int* in_sizes, int n_in,
                              void* d_out, int out_size, void* d_ws, size_t ws_size,
                              hipStream_t stream) {
  const float* E = (const float*)d_in[0];
  const float* W1 = (const float*)d_in[1];
  const float* b1 = (const float*)d_in[2];
  const float* W2 = (const float*)d_in[3];
  const float* b2 = (const float*)d_in[4];
  float* out = (float*)d_out;
  char* ws = (char*)d_ws;
  u16* E16 = (u16*)(ws + WS_E16);
  float* Aw = (float*)(ws + WS_A);
  float* Cw = (float*)(ws + WS_C);
  u16* WF = (u16*)(ws + WS_WF);

  // single prep kernel: E-cvt + out-zero (0..511) | WF emission (512..639) |
  // AC gemm f32-direct (640..895) — all block ranges independent
  hipLaunchKernelGGL(k_prep, dim3(896), dim3(256), 0, stream, E, E16, W1, WF,
                     out, Aw, Cw);
  // 272 = # of 8x16 pair-tiles intersecting the upper triangle (tj*(tj+1)+ti)
  hipLaunchKernelGGL(k_pair, dim3(272, 2, 4), dim3(256), 0, stream,
                     E16, WF, Aw, Cw, b1, W2, b2, out);
}